// Round 1
// baseline (2012.300 us; speedup 1.0000x reference)
//
#include <hip/hip_runtime.h>
#include <hip/hip_bf16.h>

// Problem constants
// B=2, L=2048, D=1024, H=16, HD=64.  M = B*L = 4096, K = D = 1024.
// q/k/v scratch layout: [B,H,L,64]  (bh-major), attn-out scratch: [B,L,H*64] (concat).

#define GM 4096
#define GK 1024
#define GL 2048
#define GH 16

// ---------------------------------------------------------------------------
// Tiled fp32 GEMM, BM=BN=64, BK=16, 256 threads, 4x4 per thread.
// headmode=1: B is [H][K][64] per-head weights, block.y = head, ldb=64.
// headmode=0: B is [K][1024] row-major, block.y = n-tile, ldb=1024.
// outmode=1:  C written as q/k/v layout [B,H,L,64] (head = block.y).
// outmode=0:  C written as [M][1024] row-major.
// ---------------------------------------------------------------------------
__global__ __launch_bounds__(256) void gemm64(
    const float* __restrict__ A, const float* __restrict__ B,
    float* __restrict__ C, int headmode, int outmode)
{
    __shared__ float As[16][65];   // [k][m], +1 pad
    __shared__ float Bs[16][64];   // [k][n]

    const int tid = threadIdx.x;
    const int tx = tid & 15;       // n-subtile 0..15
    const int ty = tid >> 4;       // m-subtile 0..15
    const int m0 = blockIdx.x * 64;
    const int by = blockIdx.y;

    const float* Bbase;
    int ldb;
    if (headmode) { Bbase = B + (size_t)by * GK * 64; ldb = 64;   }
    else          { Bbase = B + by * 64;              ldb = 1024; }

    const int arow = tid >> 2;        // 0..63
    const int akk  = (tid & 3) * 4;   // 0,4,8,12
    const int brow = tid >> 4;        // 0..15
    const int bcol = (tid & 15) * 4;  // 0..60

    float acc[4][4] = {};

    for (int k0 = 0; k0 < GK; k0 += 16) {
        float4 av = *reinterpret_cast<const float4*>(
            &A[(size_t)(m0 + arow) * GK + k0 + akk]);
        As[akk + 0][arow] = av.x;
        As[akk + 1][arow] = av.y;
        As[akk + 2][arow] = av.z;
        As[akk + 3][arow] = av.w;
        float4 bv = *reinterpret_cast<const float4*>(
            &Bbase[(size_t)(k0 + brow) * ldb + bcol]);
        *reinterpret_cast<float4*>(&Bs[brow][bcol]) = bv;
        __syncthreads();

#pragma unroll
        for (int kk = 0; kk < 16; ++kk) {
            float a[4], b[4];
#pragma unroll
            for (int i = 0; i < 4; ++i) a[i] = As[kk][ty * 4 + i];
#pragma unroll
            for (int j = 0; j < 4; ++j) b[j] = Bs[kk][tx * 4 + j];
#pragma unroll
            for (int i = 0; i < 4; ++i)
#pragma unroll
                for (int j = 0; j < 4; ++j) acc[i][j] += a[i] * b[j];
        }
        __syncthreads();
    }

    if (outmode == 0) {
#pragma unroll
        for (int i = 0; i < 4; ++i) {
            int m = m0 + ty * 4 + i;
            size_t base = (size_t)m * 1024 + by * 64 + tx * 4;
#pragma unroll
            for (int j = 0; j < 4; ++j) C[base + j] = acc[i][j];
        }
    } else {
#pragma unroll
        for (int i = 0; i < 4; ++i) {
            int m = m0 + ty * 4 + i;
            int b = m >> 11;          // /2048
            int l = m & 2047;
            size_t base = ((size_t)(b * GH + by) * GL + l) * 64 + tx * 4;
#pragma unroll
            for (int j = 0; j < 4; ++j) C[base + j] = acc[i][j];
        }
    }
}

// ---------------------------------------------------------------------------
// Causal flash attention, fp32. One block = 64 q-rows of one (b,h).
// grid = (L/64, B*H), block = 256 (16x16 threads, 4x4 per thread).
// q,k,v: [B*H][L][64].  o: [B][L][H*64] (concat layout).
// ---------------------------------------------------------------------------
__global__ __launch_bounds__(256) void attn64(
    const float* __restrict__ q, const float* __restrict__ k,
    const float* __restrict__ v, float* __restrict__ o)
{
    __shared__ float qs[64][65];
    __shared__ float ks[64][65];   // reused for V
    __shared__ float ps[64][65];

    const int tid = threadIdx.x;
    const int tx = tid & 15;
    const int ty = tid >> 4;
    const int q0 = blockIdx.x * 64;
    const int bh = blockIdx.y;
    const size_t qkbase = (size_t)bh * GL * 64;

    // load Q tile (scalar stores due to +1 pad)
    {
        const float* qg = q + qkbase + (size_t)q0 * 64;
#pragma unroll
        for (int t = 0; t < 4; ++t) {
            int fid = tid + t * 256;       // float4 index 0..1023
            int row = fid >> 4;
            int col = (fid & 15) * 4;
            float4 val = *reinterpret_cast<const float4*>(&qg[row * 64 + col]);
            qs[row][col + 0] = val.x;
            qs[row][col + 1] = val.y;
            qs[row][col + 2] = val.z;
            qs[row][col + 3] = val.w;
        }
    }

    float m_run[4], l_run[4], accO[4][4] = {};
#pragma unroll
    for (int i = 0; i < 4; ++i) { m_run[i] = -__builtin_inff(); l_run[i] = 0.f; }

    __syncthreads();

    for (int j0 = 0; j0 <= q0; j0 += 64) {
        // ---- load K tile ----
        {
            const float* kg = k + qkbase + (size_t)j0 * 64;
#pragma unroll
            for (int t = 0; t < 4; ++t) {
                int fid = tid + t * 256;
                int row = fid >> 4;
                int col = (fid & 15) * 4;
                float4 val = *reinterpret_cast<const float4*>(&kg[row * 64 + col]);
                ks[row][col + 0] = val.x;
                ks[row][col + 1] = val.y;
                ks[row][col + 2] = val.z;
                ks[row][col + 3] = val.w;
            }
        }
        __syncthreads();

        // ---- S = Q K^T * 0.125, causal mask ----
        float s[4][4] = {};
#pragma unroll
        for (int e = 0; e < 64; ++e) {
            float a[4], b[4];
#pragma unroll
            for (int i = 0; i < 4; ++i) a[i] = qs[ty * 4 + i][e];
#pragma unroll
            for (int j = 0; j < 4; ++j) b[j] = ks[tx * 4 + j][e];
#pragma unroll
            for (int i = 0; i < 4; ++i)
#pragma unroll
                for (int j = 0; j < 4; ++j) s[i][j] += a[i] * b[j];
        }
#pragma unroll
        for (int i = 0; i < 4; ++i) {
            int grow = q0 + ty * 4 + i;
#pragma unroll
            for (int j = 0; j < 4; ++j) {
                int gcol = j0 + tx * 4 + j;
                s[i][j] = (gcol > grow) ? -__builtin_inff() : s[i][j] * 0.125f;
            }
        }

        // ---- online softmax (row stats replicated across the 16-lane tx group) ----
        float rm[4], rs[4];
#pragma unroll
        for (int i = 0; i < 4; ++i) {
            rm[i] = s[i][0];
#pragma unroll
            for (int j = 1; j < 4; ++j) rm[i] = fmaxf(rm[i], s[i][j]);
        }
#pragma unroll
        for (int off = 1; off < 16; off <<= 1)
#pragma unroll
            for (int i = 0; i < 4; ++i) rm[i] = fmaxf(rm[i], __shfl_xor(rm[i], off));

        float mnew[4], scale[4];
#pragma unroll
        for (int i = 0; i < 4; ++i) {
            mnew[i] = fmaxf(m_run[i], rm[i]);
            scale[i] = __expf(m_run[i] - mnew[i]);   // m_run=-inf on tile0 -> 0
            rs[i] = 0.f;
        }
#pragma unroll
        for (int i = 0; i < 4; ++i)
#pragma unroll
            for (int j = 0; j < 4; ++j) {
                float p = __expf(s[i][j] - mnew[i]);   // masked -> exp(-inf)=0
                ps[ty * 4 + i][tx * 4 + j] = p;
                rs[i] += p;
            }
#pragma unroll
        for (int off = 1; off < 16; off <<= 1)
#pragma unroll
            for (int i = 0; i < 4; ++i) rs[i] += __shfl_xor(rs[i], off);
#pragma unroll
        for (int i = 0; i < 4; ++i) {
            l_run[i] = l_run[i] * scale[i] + rs[i];
            m_run[i] = mnew[i];
#pragma unroll
            for (int j = 0; j < 4; ++j) accO[i][j] *= scale[i];
        }
        __syncthreads();   // ps written; everyone done with ks (K)

        // ---- load V tile into ks ----
        {
            const float* vg = v + qkbase + (size_t)j0 * 64;
#pragma unroll
            for (int t = 0; t < 4; ++t) {
                int fid = tid + t * 256;
                int row = fid >> 4;
                int col = (fid & 15) * 4;
                float4 val = *reinterpret_cast<const float4*>(&vg[row * 64 + col]);
                ks[row][col + 0] = val.x;
                ks[row][col + 1] = val.y;
                ks[row][col + 2] = val.z;
                ks[row][col + 3] = val.w;
            }
        }
        __syncthreads();

        // ---- O += P V ----
#pragma unroll
        for (int kv = 0; kv < 64; ++kv) {
            float a[4], b[4];
#pragma unroll
            for (int i = 0; i < 4; ++i) a[i] = ps[ty * 4 + i][kv];
#pragma unroll
            for (int j = 0; j < 4; ++j) b[j] = ks[kv][tx * 4 + j];
#pragma unroll
            for (int i = 0; i < 4; ++i)
#pragma unroll
                for (int j = 0; j < 4; ++j) accO[i][j] += a[i] * b[j];
        }
        __syncthreads();   // done with ks/ps before next iteration
    }

    // ---- epilogue: write concat layout [B][L][H*64] ----
    const int b = bh >> 4;
    const int h = bh & 15;
#pragma unroll
    for (int i = 0; i < 4; ++i) {
        int row = q0 + ty * 4 + i;
        float inv = 1.f / l_run[i];
        size_t base = ((size_t)b * GL + row) * 1024 + h * 64 + tx * 4;
#pragma unroll
        for (int j = 0; j < 4; ++j) o[base + j] = accO[i][j] * inv;
    }
}

// ---------------------------------------------------------------------------
extern "C" void kernel_launch(void* const* d_in, const int* in_sizes, int n_in,
                              void* d_out, int out_size, void* d_ws, size_t ws_size,
                              hipStream_t stream) {
    const float* emb = (const float*)d_in[0];
    const float* Wq  = (const float*)d_in[1];
    const float* Wk  = (const float*)d_in[2];
    const float* Wv  = (const float*)d_in[3];
    const float* Wo  = (const float*)d_in[4];
    float* out = (float*)d_out;

    const size_t elems = (size_t)GM * 1024;  // 4,194,304 floats per buffer
    float* qb = (float*)d_ws;
    float* kb = qb + elems;
    float* vb = kb + elems;
    float* ab = vb + elems;

    dim3 blk(256);
    dim3 gg(GM / 64, 16);

    gemm64<<<gg, blk, 0, stream>>>(emb, Wq, qb, 1, 1);
    gemm64<<<gg, blk, 0, stream>>>(emb, Wk, kb, 1, 1);
    gemm64<<<gg, blk, 0, stream>>>(emb, Wv, vb, 1, 1);
    attn64<<<dim3(GL / 64, 32), blk, 0, stream>>>(qb, kb, vb, ab);
    gemm64<<<gg, blk, 0, stream>>>(ab, Wo, out, 0, 0);
}

// Round 2
// 584.653 us; speedup vs baseline: 3.4419x; 3.4419x over previous
//
#include <hip/hip_runtime.h>
#include <hip/hip_bf16.h>

// B=2, L=2048, D=1024, H=16, HD=64.  M = B*L = 4096, K = D = 1024.
// ws layout: qb bf16 [B*H][L][64] (8MB), kb bf16 same (8MB),
//            vtb bf16 [B*H][64][L] (8MB, V transposed), ab fp32 [B][L][1024] (16MB).

#define GM 4096
#define GK 1024
#define GL 2048
#define GH 16

typedef __attribute__((ext_vector_type(8))) short bf16x8;
typedef __attribute__((ext_vector_type(4))) float f32x4;

__device__ inline unsigned pack_bf16(float a, float b) {
    __hip_bfloat16 ha = __float2bfloat16(a);
    __hip_bfloat16 hb = __float2bfloat16(b);
    unsigned short ua = *reinterpret_cast<unsigned short*>(&ha);
    unsigned short ub = *reinterpret_cast<unsigned short*>(&hb);
    return ((unsigned)ub << 16) | ua;
}

// ---------------------------------------------------------------------------
// fp32 tiled GEMM, BM=BN=64, BK=16, 256 threads, 4x4/thread (core unchanged).
// headmode=1: B=[H][K][64] per-head weights (block.y=head). headmode=0: B=[K][1024].
// outmode 0: fp32 [M][1024]
// outmode 1: bf16 [bh][L][64]     (q, k for attention)
// outmode 2: bf16 [bh][64][L]     (v transposed for attention)
// ---------------------------------------------------------------------------
__global__ __launch_bounds__(256) void gemm64(
    const float* __restrict__ A, const float* __restrict__ B,
    void* __restrict__ Cv, int headmode, int outmode)
{
    __shared__ float As[16][65];   // [k][m], +1 pad
    __shared__ float Bs[16][64];   // [k][n]

    const int tid = threadIdx.x;
    const int tx = tid & 15;
    const int ty = tid >> 4;
    const int m0 = blockIdx.x * 64;
    const int by = blockIdx.y;

    const float* Bbase;
    int ldb;
    if (headmode) { Bbase = B + (size_t)by * GK * 64; ldb = 64;   }
    else          { Bbase = B + by * 64;              ldb = 1024; }

    const int arow = tid >> 2;
    const int akk  = (tid & 3) * 4;
    const int brow = tid >> 4;
    const int bcol = (tid & 15) * 4;

    float acc[4][4] = {};

    for (int k0 = 0; k0 < GK; k0 += 16) {
        float4 av = *reinterpret_cast<const float4*>(
            &A[(size_t)(m0 + arow) * GK + k0 + akk]);
        As[akk + 0][arow] = av.x;
        As[akk + 1][arow] = av.y;
        As[akk + 2][arow] = av.z;
        As[akk + 3][arow] = av.w;
        float4 bv = *reinterpret_cast<const float4*>(
            &Bbase[(size_t)(k0 + brow) * ldb + bcol]);
        *reinterpret_cast<float4*>(&Bs[brow][bcol]) = bv;
        __syncthreads();

#pragma unroll
        for (int kk = 0; kk < 16; ++kk) {
            float a[4], b[4];
#pragma unroll
            for (int i = 0; i < 4; ++i) a[i] = As[kk][ty * 4 + i];
#pragma unroll
            for (int j = 0; j < 4; ++j) b[j] = Bs[kk][tx * 4 + j];
#pragma unroll
            for (int i = 0; i < 4; ++i)
#pragma unroll
                for (int j = 0; j < 4; ++j) acc[i][j] += a[i] * b[j];
        }
        __syncthreads();
    }

    if (outmode == 0) {
        float* C = (float*)Cv;
#pragma unroll
        for (int i = 0; i < 4; ++i) {
            int m = m0 + ty * 4 + i;
            size_t base = (size_t)m * 1024 + by * 64 + tx * 4;
#pragma unroll
            for (int j = 0; j < 4; ++j) C[base + j] = acc[i][j];
        }
    } else if (outmode == 1) {
        __hip_bfloat16* C = (__hip_bfloat16*)Cv;
#pragma unroll
        for (int i = 0; i < 4; ++i) {
            int m = m0 + ty * 4 + i;
            int b = m >> 11;
            int l = m & 2047;
            size_t base = ((size_t)(b * GH + by) * GL + l) * 64 + tx * 4;
#pragma unroll
            for (int j = 0; j < 4; ++j) C[base + j] = __float2bfloat16(acc[i][j]);
        }
    } else {
        __hip_bfloat16* C = (__hip_bfloat16*)Cv;
#pragma unroll
        for (int i = 0; i < 4; ++i) {
            int m = m0 + ty * 4 + i;
            int b = m >> 11;
            int l = m & 2047;
#pragma unroll
            for (int j = 0; j < 4; ++j) {
                int hd = tx * 4 + j;
                C[((size_t)(b * GH + by) * 64 + hd) * GL + l] = __float2bfloat16(acc[i][j]);
            }
        }
    }
}

// ---------------------------------------------------------------------------
// bf16 MFMA causal flash attention (swapped-operand structure).
// grid=(L/64, B*H), block=256 (4 waves). Wave w owns q-rows q0+16w..+15.
// q,k: bf16 [bh][L][64]; vt: bf16 [bh][64][L]; o: fp32 [B][L][H*64].
//
// QK^T: S^T = mfma(A=K_frag, B=Q_frag) -> lane holds one q-row (col=lane&15),
// 16 k-vals (4 nt-tiles x 4 regs, kcol = nt*16 + g*4 + reg, g=lane>>4).
// Softmax: 16 local + shfl_xor(16,32). PV: O^T = mfma(A=Vt_frag, B=Pt_frag),
// P staged per-wave in LDS. All LDS tiles XOR-swizzled (chunk ^= row&7).
// ---------------------------------------------------------------------------
__global__ __launch_bounds__(256) void attn_mfma(
    const __hip_bfloat16* __restrict__ qg,
    const __hip_bfloat16* __restrict__ kg,
    const __hip_bfloat16* __restrict__ vtg,
    float* __restrict__ og)
{
    __shared__ uint4 Ks[512];      // [64 k-rows][8 chunks of 16B], swizzled
    __shared__ uint4 Vs[512];      // [64 hd-rows][8 chunks], swizzled
    __shared__ uint2 Ps[4][256];   // per-wave P [16 q][64 k] bf16, swizzled

    const int tid  = threadIdx.x;
    const int lane = tid & 63;
    const int w    = tid >> 6;
    const int col  = lane & 15;    // q-row within wave (swapped layout)
    const int g    = lane >> 4;    // 0..3
    const int q0   = blockIdx.x * 64;
    const int bh   = blockIdx.y;
    const size_t qkb  = (size_t)bh * GL * 64;
    const size_t vtbo = (size_t)bh * 64 * GL;

    // Q fragments in registers: lane holds Q[qrow][c*32 + g*8 + e]
    const int qrow = q0 + w * 16 + col;
    bf16x8 qf[2];
    qf[0] = *reinterpret_cast<const bf16x8*>(qg + qkb + (size_t)qrow * 64 + g * 8);
    qf[1] = *reinterpret_cast<const bf16x8*>(qg + qkb + (size_t)qrow * 64 + 32 + g * 8);

    float m_run = -__builtin_inff();
    float l_run = 0.f;
    f32x4 o_acc[4];
#pragma unroll
    for (int nt = 0; nt < 4; ++nt) o_acc[nt] = f32x4{0.f, 0.f, 0.f, 0.f};

    const int nkv = blockIdx.x + 1;
    for (int t = 0; t < nkv; ++t) {
        const int j0 = t * 64;
        // ---- stage K tile and Vt tile (swizzled ds_write_b128) ----
#pragma unroll
        for (int s2 = 0; s2 < 2; ++s2) {
            int c  = tid + s2 * 256;       // 0..511
            int row = c >> 3, cc = c & 7;
            int swz = cc ^ (row & 7);
            Ks[row * 8 + swz] = *reinterpret_cast<const uint4*>(
                kg + qkb + (size_t)(j0 + row) * 64 + cc * 8);
            Vs[row * 8 + swz] = *reinterpret_cast<const uint4*>(
                vtg + vtbo + (size_t)row * GL + j0 + cc * 8);
        }
        __syncthreads();

        // ---- S^T = K . Q^T ----
        f32x4 st[4];
#pragma unroll
        for (int nt = 0; nt < 4; ++nt) {
            int row = nt * 16 + col;
            bf16x8 kf0 = *reinterpret_cast<const bf16x8*>(&Ks[row * 8 + ( g      ^ (row & 7))]);
            bf16x8 kf1 = *reinterpret_cast<const bf16x8*>(&Ks[row * 8 + ((4 + g) ^ (row & 7))]);
            f32x4 z = f32x4{0.f, 0.f, 0.f, 0.f};
            z      = __builtin_amdgcn_mfma_f32_16x16x32_bf16(kf0, qf[0], z, 0, 0, 0);
            st[nt] = __builtin_amdgcn_mfma_f32_16x16x32_bf16(kf1, qf[1], z, 0, 0, 0);
        }

        // ---- mask + scale + online softmax (one q-row per lane) ----
        float mx = -__builtin_inff();
#pragma unroll
        for (int nt = 0; nt < 4; ++nt)
#pragma unroll
            for (int r = 0; r < 4; ++r) {
                int kcol = j0 + nt * 16 + g * 4 + r;
                float s = (kcol <= qrow) ? st[nt][r] * 0.125f : -__builtin_inff();
                st[nt][r] = s;
                mx = fmaxf(mx, s);
            }
        mx = fmaxf(mx, __shfl_xor(mx, 16));
        mx = fmaxf(mx, __shfl_xor(mx, 32));
        const float mnew = fmaxf(m_run, mx);
        const float scl  = __expf(m_run - mnew);   // first tile: exp(-inf)=0
        float rsum = 0.f;
        unsigned pk[4][2];
#pragma unroll
        for (int nt = 0; nt < 4; ++nt) {
            float p0 = __expf(st[nt][0] - mnew);
            float p1 = __expf(st[nt][1] - mnew);
            float p2 = __expf(st[nt][2] - mnew);
            float p3 = __expf(st[nt][3] - mnew);
            rsum += (p0 + p1) + (p2 + p3);
            pk[nt][0] = pack_bf16(p0, p1);
            pk[nt][1] = pack_bf16(p2, p3);
        }
        rsum += __shfl_xor(rsum, 16);
        rsum += __shfl_xor(rsum, 32);
        l_run = l_run * scl + rsum;
        m_run = mnew;
#pragma unroll
        for (int nt = 0; nt < 4; ++nt) {
            o_acc[nt][0] *= scl; o_acc[nt][1] *= scl;
            o_acc[nt][2] *= scl; o_acc[nt][3] *= scl;
        }

        // ---- P -> per-wave LDS (swizzled), re-read as B-fragment of P^T ----
        uint2* Pw = Ps[w];
#pragma unroll
        for (int nt = 0; nt < 4; ++nt) {
            // k = nt*16 + g*4 + {0..3} at row q=col; 8B unit idx = nt*4+g
            int unit = (((nt * 2 + (g >> 1)) ^ (col & 7)) << 1) | (g & 1);
            uint2 u; u.x = pk[nt][0]; u.y = pk[nt][1];
            Pw[col * 16 + unit] = u;
        }
        bf16x8 pf[2];
#pragma unroll
        for (int c = 0; c < 2; ++c) {
            int chunk = (c * 4 + g) ^ (col & 7);
            pf[c] = *reinterpret_cast<const bf16x8*>(&Pw[col * 16 + chunk * 2]);
        }

        // ---- O^T += V^T . P^T ----
#pragma unroll
        for (int nt = 0; nt < 4; ++nt) {
            int row = nt * 16 + col;   // hd row in Vs
            bf16x8 vf0 = *reinterpret_cast<const bf16x8*>(&Vs[row * 8 + ( g      ^ (row & 7))]);
            bf16x8 vf1 = *reinterpret_cast<const bf16x8*>(&Vs[row * 8 + ((4 + g) ^ (row & 7))]);
            o_acc[nt] = __builtin_amdgcn_mfma_f32_16x16x32_bf16(vf0, pf[0], o_acc[nt], 0, 0, 0);
            o_acc[nt] = __builtin_amdgcn_mfma_f32_16x16x32_bf16(vf1, pf[1], o_acc[nt], 0, 0, 0);
        }
        __syncthreads();
    }

    // ---- epilogue: O[q][hd] = o_acc / l_run -> concat fp32 [B][L][H*64] ----
    const int b = bh >> 4, h = bh & 15;
    const float inv = 1.f / l_run;
#pragma unroll
    for (int nt = 0; nt < 4; ++nt) {
        float4 ov;
        ov.x = o_acc[nt][0] * inv;
        ov.y = o_acc[nt][1] * inv;
        ov.z = o_acc[nt][2] * inv;
        ov.w = o_acc[nt][3] * inv;
        *reinterpret_cast<float4*>(
            og + ((size_t)(b * GL + qrow)) * 1024 + h * 64 + nt * 16 + g * 4) = ov;
    }
}

// ---------------------------------------------------------------------------
extern "C" void kernel_launch(void* const* d_in, const int* in_sizes, int n_in,
                              void* d_out, int out_size, void* d_ws, size_t ws_size,
                              hipStream_t stream) {
    const float* emb = (const float*)d_in[0];
    const float* Wq  = (const float*)d_in[1];
    const float* Wk  = (const float*)d_in[2];
    const float* Wv  = (const float*)d_in[3];
    const float* Wo  = (const float*)d_in[4];
    float* out = (float*)d_out;

    char* ws = (char*)d_ws;
    __hip_bfloat16* qb  = (__hip_bfloat16*)(ws);                       // 8 MB
    __hip_bfloat16* kb  = (__hip_bfloat16*)(ws + (8u << 20));          // 8 MB
    __hip_bfloat16* vtb = (__hip_bfloat16*)(ws + (16u << 20));         // 8 MB
    float*          ab  = (float*)         (ws + (24u << 20));         // 16 MB

    dim3 blk(256);
    dim3 gg(GM / 64, 16);

    gemm64<<<gg, blk, 0, stream>>>(emb, Wq, qb,  1, 1);
    gemm64<<<gg, blk, 0, stream>>>(emb, Wk, kb,  1, 1);
    gemm64<<<gg, blk, 0, stream>>>(emb, Wv, vtb, 1, 2);
    attn_mfma<<<dim3(GL / 64, 32), blk, 0, stream>>>(qb, kb, vtb, ab);
    gemm64<<<gg, blk, 0, stream>>>(ab, Wo, out, 0, 0);
}

// Round 3
// 161.107 us; speedup vs baseline: 12.4905x; 3.6290x over previous
//
#include <hip/hip_runtime.h>
#include <hip/hip_bf16.h>

// B=2, L=2048, D=1024, H=16, HD=64.  M = B*L = 4096, K = D = 1024.
// ws (bytes):
//   qb   @ 0MB   bf16 [32][2048][64]
//   kb   @ 8MB   bf16 [32][2048][64]
//   vtb  @16MB   bf16 [32][64][2048]   (V transposed)
//   ab   @24MB   bf16 [4096][1024]     (attn concat out)
//   embb @32MB   bf16 [4096][1024]
//   wqt  @40MB   bf16 [16][64][1024]   (transposed per-head weights)
//   wkt  @42MB   wvt @44MB   wot @46MB bf16 [1024][1024] transposed

#define GM 4096
#define GK 1024
#define GL 2048
#define GH 16

typedef __attribute__((ext_vector_type(8))) short bf16x8;
typedef __attribute__((ext_vector_type(4))) float f32x4;
typedef unsigned short u16;

__device__ __forceinline__ u16 bfu(float x) {
    __hip_bfloat16 h = __float2bfloat16(x);
    return *reinterpret_cast<u16*>(&h);
}
__device__ __forceinline__ unsigned pack_bf16(float a, float b) {
    return ((unsigned)bfu(b) << 16) | bfu(a);
}
__device__ __forceinline__ void gl_lds16(const void* g, void* l) {
    __builtin_amdgcn_global_load_lds(
        (__attribute__((address_space(1))) void*)(g),
        (__attribute__((address_space(3))) void*)(l),
        16, 0, 0);
}

// ---------------------------------------------------------------------------
// fp32 -> bf16 cast, 8 elements/thread.
// ---------------------------------------------------------------------------
__global__ __launch_bounds__(256) void cast_bf16(
    const float* __restrict__ src, u16* __restrict__ dst, int n8)
{
    int i = blockIdx.x * 256 + threadIdx.x;
    if (i >= n8) return;
    float4 v0 = reinterpret_cast<const float4*>(src)[i * 2];
    float4 v1 = reinterpret_cast<const float4*>(src)[i * 2 + 1];
    uint4 o;
    o.x = pack_bf16(v0.x, v0.y);
    o.y = pack_bf16(v0.z, v0.w);
    o.z = pack_bf16(v1.x, v1.y);
    o.w = pack_bf16(v1.z, v1.w);
    reinterpret_cast<uint4*>(dst)[i] = o;
}

// ---------------------------------------------------------------------------
// Transpose+convert: src fp32 [G][R][C] -> dst bf16 [G][C][R].  64x64 tiles.
// grid = (R/64, C/64, G), block = 256.
// ---------------------------------------------------------------------------
__global__ __launch_bounds__(256) void transpose_bf16(
    const float* __restrict__ src, u16* __restrict__ dst, int R, int C)
{
    __shared__ float T[64][65];
    const int t = threadIdx.x;
    const int r0 = blockIdx.x * 64, c0 = blockIdx.y * 64;
    const float* s = src + (size_t)blockIdx.z * R * C;
    u16* d = dst + (size_t)blockIdx.z * R * C;
#pragma unroll
    for (int i = 0; i < 4; ++i) {
        int idx = i * 256 + t;
        int row = idx >> 4, col = (idx & 15) * 4;
        float4 v = *reinterpret_cast<const float4*>(&s[(size_t)(r0 + row) * C + c0 + col]);
        T[row][col] = v.x; T[row][col + 1] = v.y;
        T[row][col + 2] = v.z; T[row][col + 3] = v.w;
    }
    __syncthreads();
#pragma unroll
    for (int i = 0; i < 4; ++i) {
        int idx = i * 256 + t;
        int oc = idx >> 4, ok = (idx & 15) * 4;
        ushort4 o;
        o.x = bfu(T[ok][oc]);     o.y = bfu(T[ok + 1][oc]);
        o.z = bfu(T[ok + 2][oc]); o.w = bfu(T[ok + 3][oc]);
        *reinterpret_cast<ushort4*>(&d[(size_t)(c0 + oc) * R + r0 + ok]) = o;
    }
}

// ---------------------------------------------------------------------------
// bf16 MFMA GEMM.  C[M=4096, n-tile by*64] = A[4096,1024] x Bt[by][64,1024]^T.
// BM=128, BN=64, BK=64, 256 threads (4 waves, 2x2). m97 structure:
// global_load_lds(16B) staging, pre-swizzled source (chunk ^= row&7),
// swizzled ds_read_b128, 16 mfma/K-step/wave, 2 barriers/K-step.
// outmode 0: fp32 [4096][1024]          (by = n-tile)
// outmode 1: bf16 [b*16+by][2048][64]   (q/k; by = head)
// outmode 2: bf16 [b*16+by][64][2048]   (v transposed; by = head)
// ---------------------------------------------------------------------------
__global__ __launch_bounds__(256) void gemm_mfma(
    const u16* __restrict__ A, const u16* __restrict__ Bt,
    void* __restrict__ Cv, int outmode)
{
    __shared__ u16 As[128 * 64];   // [m][k], swizzled 16B chunks
    __shared__ u16 Bs[64 * 64];    // [n][k], swizzled

    const int tid  = threadIdx.x;
    const int lane = tid & 63;
    const int w    = tid >> 6;
    const int g    = lane >> 4;
    const int c15  = lane & 15;
    const int wr   = w >> 1, wc = w & 1;
    const int m0   = blockIdx.x * 128;
    const int by   = blockIdx.y;

    const u16* Bb = Bt + (size_t)by * (64 * 1024);
    const int srow8  = lane >> 3;   // 0..7
    const int schunk = lane & 7;

    f32x4 acc[4][2];
#pragma unroll
    for (int mf = 0; mf < 4; ++mf)
#pragma unroll
        for (int nf = 0; nf < 2; ++nf) acc[mf][nf] = f32x4{0.f, 0.f, 0.f, 0.f};

    for (int k0 = 0; k0 < GK; k0 += 64) {
        // stage A: 128x64 bf16 (16KB) in 4 calls
#pragma unroll
        for (int c = 0; c < 4; ++c) {
            int row = c * 32 + w * 8 + srow8;
            int gc = schunk ^ (row & 7);
            gl_lds16(A + (size_t)(m0 + row) * GK + k0 + gc * 8,
                     As + c * 2048 + w * 512);
        }
        // stage B: 64x64 bf16 (8KB) in 2 calls
#pragma unroll
        for (int c = 0; c < 2; ++c) {
            int row = c * 32 + w * 8 + srow8;
            int gc = schunk ^ (row & 7);
            gl_lds16(Bb + (size_t)row * GK + k0 + gc * 8,
                     Bs + c * 2048 + w * 512);
        }
        __syncthreads();   // drains vmcnt -> tile visible

#pragma unroll
        for (int kc = 0; kc < 2; ++kc) {
            bf16x8 a[4], b[2];
#pragma unroll
            for (int mf = 0; mf < 4; ++mf) {
                int row = wr * 64 + mf * 16 + c15;
                int ch = (kc * 4 + g) ^ (row & 7);
                a[mf] = *reinterpret_cast<const bf16x8*>(As + row * 64 + ch * 8);
            }
#pragma unroll
            for (int nf = 0; nf < 2; ++nf) {
                int row = wc * 32 + nf * 16 + c15;
                int ch = (kc * 4 + g) ^ (row & 7);
                b[nf] = *reinterpret_cast<const bf16x8*>(Bs + row * 64 + ch * 8);
            }
#pragma unroll
            for (int mf = 0; mf < 4; ++mf)
#pragma unroll
                for (int nf = 0; nf < 2; ++nf)
                    acc[mf][nf] = __builtin_amdgcn_mfma_f32_16x16x32_bf16(
                        a[mf], b[nf], acc[mf][nf], 0, 0, 0);
        }
        __syncthreads();   // all reads done before restaging
    }

    // ---- epilogue ----
    if (outmode == 0) {
        float* C = (float*)Cv;
#pragma unroll
        for (int mf = 0; mf < 4; ++mf) {
            int m = m0 + wr * 64 + mf * 16 + g * 4;
#pragma unroll
            for (int nf = 0; nf < 2; ++nf) {
                int n = by * 64 + wc * 32 + nf * 16 + c15;
#pragma unroll
                for (int r = 0; r < 4; ++r)
                    C[(size_t)(m + r) * 1024 + n] = acc[mf][nf][r];
            }
        }
    } else if (outmode == 1) {
        u16* C = (u16*)Cv;
        const int b = m0 >> 11, l0 = m0 & 2047;
        const size_t bh = ((size_t)(b * GH + by)) * GL * 64;
#pragma unroll
        for (int mf = 0; mf < 4; ++mf) {
            int l = l0 + wr * 64 + mf * 16 + g * 4;
#pragma unroll
            for (int nf = 0; nf < 2; ++nf) {
                int n = wc * 32 + nf * 16 + c15;
#pragma unroll
                for (int r = 0; r < 4; ++r)
                    C[bh + (size_t)(l + r) * 64 + n] = bfu(acc[mf][nf][r]);
            }
        }
    } else {
        u16* C = (u16*)Cv;
        const int b = m0 >> 11, l0 = m0 & 2047;
        const size_t bh = ((size_t)(b * GH + by)) * 64 * GL;
#pragma unroll
        for (int mf = 0; mf < 4; ++mf) {
            int l = l0 + wr * 64 + mf * 16 + g * 4;
#pragma unroll
            for (int nf = 0; nf < 2; ++nf) {
                int n = wc * 32 + nf * 16 + c15;
                ushort4 o;
                o.x = bfu(acc[mf][nf][0]); o.y = bfu(acc[mf][nf][1]);
                o.z = bfu(acc[mf][nf][2]); o.w = bfu(acc[mf][nf][3]);
                *reinterpret_cast<ushort4*>(&C[bh + (size_t)n * GL + l]) = o;
            }
        }
    }
}

// ---------------------------------------------------------------------------
// bf16 MFMA causal flash attention (unchanged core; bf16 epilogue).
// grid=(L/64, B*H), block=256 (4 waves). q,k: bf16 [bh][L][64];
// vt: bf16 [bh][64][L]; o: bf16 [B][L][H*64].
// ---------------------------------------------------------------------------
__global__ __launch_bounds__(256) void attn_mfma(
    const u16* __restrict__ qg, const u16* __restrict__ kg,
    const u16* __restrict__ vtg, u16* __restrict__ og)
{
    __shared__ uint4 Ks[512];
    __shared__ uint4 Vs[512];
    __shared__ uint2 Ps[4][256];

    const int tid  = threadIdx.x;
    const int lane = tid & 63;
    const int w    = tid >> 6;
    const int col  = lane & 15;
    const int g    = lane >> 4;
    const int q0   = blockIdx.x * 64;
    const int bh   = blockIdx.y;
    const size_t qkb  = (size_t)bh * GL * 64;
    const size_t vtbo = (size_t)bh * 64 * GL;

    const int qrow = q0 + w * 16 + col;
    bf16x8 qf[2];
    qf[0] = *reinterpret_cast<const bf16x8*>(qg + qkb + (size_t)qrow * 64 + g * 8);
    qf[1] = *reinterpret_cast<const bf16x8*>(qg + qkb + (size_t)qrow * 64 + 32 + g * 8);

    float m_run = -__builtin_inff();
    float l_run = 0.f;
    f32x4 o_acc[4];
#pragma unroll
    for (int nt = 0; nt < 4; ++nt) o_acc[nt] = f32x4{0.f, 0.f, 0.f, 0.f};

    const int nkv = blockIdx.x + 1;
    for (int t = 0; t < nkv; ++t) {
        const int j0 = t * 64;
#pragma unroll
        for (int s2 = 0; s2 < 2; ++s2) {
            int c = tid + s2 * 256;
            int row = c >> 3, cc = c & 7;
            int swz = cc ^ (row & 7);
            Ks[row * 8 + swz] = *reinterpret_cast<const uint4*>(
                kg + qkb + (size_t)(j0 + row) * 64 + cc * 8);
            Vs[row * 8 + swz] = *reinterpret_cast<const uint4*>(
                vtg + vtbo + (size_t)row * GL + j0 + cc * 8);
        }
        __syncthreads();

        f32x4 st[4];
#pragma unroll
        for (int nt = 0; nt < 4; ++nt) {
            int row = nt * 16 + col;
            bf16x8 kf0 = *reinterpret_cast<const bf16x8*>(&Ks[row * 8 + ( g      ^ (row & 7))]);
            bf16x8 kf1 = *reinterpret_cast<const bf16x8*>(&Ks[row * 8 + ((4 + g) ^ (row & 7))]);
            f32x4 z = f32x4{0.f, 0.f, 0.f, 0.f};
            z      = __builtin_amdgcn_mfma_f32_16x16x32_bf16(kf0, qf[0], z, 0, 0, 0);
            st[nt] = __builtin_amdgcn_mfma_f32_16x16x32_bf16(kf1, qf[1], z, 0, 0, 0);
        }

        float mx = -__builtin_inff();
#pragma unroll
        for (int nt = 0; nt < 4; ++nt)
#pragma unroll
            for (int r = 0; r < 4; ++r) {
                int kcol = j0 + nt * 16 + g * 4 + r;
                float s = (kcol <= qrow) ? st[nt][r] * 0.125f : -__builtin_inff();
                st[nt][r] = s;
                mx = fmaxf(mx, s);
            }
        mx = fmaxf(mx, __shfl_xor(mx, 16));
        mx = fmaxf(mx, __shfl_xor(mx, 32));
        const float mnew = fmaxf(m_run, mx);
        const float scl  = __expf(m_run - mnew);
        float rsum = 0.f;
        unsigned pk[4][2];
#pragma unroll
        for (int nt = 0; nt < 4; ++nt) {
            float p0 = __expf(st[nt][0] - mnew);
            float p1 = __expf(st[nt][1] - mnew);
            float p2 = __expf(st[nt][2] - mnew);
            float p3 = __expf(st[nt][3] - mnew);
            rsum += (p0 + p1) + (p2 + p3);
            pk[nt][0] = pack_bf16(p0, p1);
            pk[nt][1] = pack_bf16(p2, p3);
        }
        rsum += __shfl_xor(rsum, 16);
        rsum += __shfl_xor(rsum, 32);
        l_run = l_run * scl + rsum;
        m_run = mnew;
#pragma unroll
        for (int nt = 0; nt < 4; ++nt) {
            o_acc[nt][0] *= scl; o_acc[nt][1] *= scl;
            o_acc[nt][2] *= scl; o_acc[nt][3] *= scl;
        }

        uint2* Pw = Ps[w];
#pragma unroll
        for (int nt = 0; nt < 4; ++nt) {
            int unit = (((nt * 2 + (g >> 1)) ^ (col & 7)) << 1) | (g & 1);
            uint2 u; u.x = pk[nt][0]; u.y = pk[nt][1];
            Pw[col * 16 + unit] = u;
        }
        bf16x8 pf[2];
#pragma unroll
        for (int c = 0; c < 2; ++c) {
            int chunk = (c * 4 + g) ^ (col & 7);
            pf[c] = *reinterpret_cast<const bf16x8*>(&Pw[col * 16 + chunk * 2]);
        }

#pragma unroll
        for (int nt = 0; nt < 4; ++nt) {
            int row = nt * 16 + col;
            bf16x8 vf0 = *reinterpret_cast<const bf16x8*>(&Vs[row * 8 + ( g      ^ (row & 7))]);
            bf16x8 vf1 = *reinterpret_cast<const bf16x8*>(&Vs[row * 8 + ((4 + g) ^ (row & 7))]);
            o_acc[nt] = __builtin_amdgcn_mfma_f32_16x16x32_bf16(vf0, pf[0], o_acc[nt], 0, 0, 0);
            o_acc[nt] = __builtin_amdgcn_mfma_f32_16x16x32_bf16(vf1, pf[1], o_acc[nt], 0, 0, 0);
        }
        __syncthreads();
    }

    const int b = bh >> 4, h = bh & 15;
    const float inv = 1.f / l_run;
#pragma unroll
    for (int nt = 0; nt < 4; ++nt) {
        ushort4 ov;
        ov.x = bfu(o_acc[nt][0] * inv);
        ov.y = bfu(o_acc[nt][1] * inv);
        ov.z = bfu(o_acc[nt][2] * inv);
        ov.w = bfu(o_acc[nt][3] * inv);
        *reinterpret_cast<ushort4*>(
            og + ((size_t)(b * GL + qrow)) * 1024 + h * 64 + nt * 16 + g * 4) = ov;
    }
}

// ---------------------------------------------------------------------------
extern "C" void kernel_launch(void* const* d_in, const int* in_sizes, int n_in,
                              void* d_out, int out_size, void* d_ws, size_t ws_size,
                              hipStream_t stream) {
    const float* emb = (const float*)d_in[0];
    const float* Wq  = (const float*)d_in[1];
    const float* Wk  = (const float*)d_in[2];
    const float* Wv  = (const float*)d_in[3];
    const float* Wo  = (const float*)d_in[4];
    float* out = (float*)d_out;

    char* ws = (char*)d_ws;
    u16* qb   = (u16*)(ws);
    u16* kb   = (u16*)(ws + ( 8u << 20));
    u16* vtb  = (u16*)(ws + (16u << 20));
    u16* ab   = (u16*)(ws + (24u << 20));
    u16* embb = (u16*)(ws + (32u << 20));
    u16* wqt  = (u16*)(ws + (40u << 20));
    u16* wkt  = (u16*)(ws + (42u << 20));
    u16* wvt  = (u16*)(ws + (44u << 20));
    u16* wot  = (u16*)(ws + (46u << 20));

    dim3 blk(256);

    // conversions
    cast_bf16<<<dim3((GM * GK / 8 + 255) / 256), blk, 0, stream>>>(emb, embb, GM * GK / 8);
    transpose_bf16<<<dim3(16, 1, 16), blk, 0, stream>>>(Wq, wqt, 1024, 64);
    transpose_bf16<<<dim3(16, 1, 16), blk, 0, stream>>>(Wk, wkt, 1024, 64);
    transpose_bf16<<<dim3(16, 1, 16), blk, 0, stream>>>(Wv, wvt, 1024, 64);
    transpose_bf16<<<dim3(16, 16, 1), blk, 0, stream>>>(Wo, wot, 1024, 1024);

    // projections
    dim3 gg(GM / 128, 16);
    gemm_mfma<<<gg, blk, 0, stream>>>(embb, wqt, qb,  1);
    gemm_mfma<<<gg, blk, 0, stream>>>(embb, wkt, kb,  1);
    gemm_mfma<<<gg, blk, 0, stream>>>(embb, wvt, vtb, 2);

    // attention
    attn_mfma<<<dim3(GL / 64, 32), blk, 0, stream>>>(qb, kb, vtb, ab);

    // output projection
    gemm_mfma<<<gg, blk, 0, stream>>>(ab, wot, out, 0);
}

// Round 4
// 121.339 us; speedup vs baseline: 16.5841x; 1.3277x over previous
//
#include <hip/hip_runtime.h>
#include <hip/hip_bf16.h>

// B=2, L=2048, D=1024, H=16, HD=64.  M = B*L = 4096, K = D = 1024.
// ws (bytes):
//   qb   @ 0MB   bf16 [32][2048][64]
//   kb   @ 8MB   bf16 [32][2048][64]
//   vtb  @16MB   bf16 [32][64][2048]   (V transposed)
//   ab   @24MB   bf16 [4096][1024]     (attn concat out)
//   embb @32MB   bf16 [4096][1024]
//   wqt  @40MB   bf16 [48][64][1024]   (wqt/wkt/wvt contiguous, 2MB each)
//   wot  @46MB   bf16 [1024][1024]     (Wo transposed)

#define GM 4096
#define GK 1024
#define GL 2048
#define GH 16

typedef __attribute__((ext_vector_type(8))) short bf16x8;
typedef __attribute__((ext_vector_type(4))) float f32x4;
typedef unsigned short u16;

__device__ __forceinline__ u16 bfu(float x) {
    __hip_bfloat16 h = __float2bfloat16(x);
    return *reinterpret_cast<u16*>(&h);
}
__device__ __forceinline__ unsigned pack_bf16(float a, float b) {
    return ((unsigned)bfu(b) << 16) | bfu(a);
}
__device__ __forceinline__ void gl_lds16(const void* g, void* l) {
    __builtin_amdgcn_global_load_lds(
        (__attribute__((address_space(1))) void*)(g),
        (__attribute__((address_space(3))) void*)(l),
        16, 0, 0);
}
__device__ __forceinline__ float fexp2(float x) {
#if __has_builtin(__builtin_amdgcn_exp2f)
    return __builtin_amdgcn_exp2f(x);
#else
    return __expf(x * 0.6931471805599453f);
#endif
}

// 0.125 (1/sqrt(64)) folded with log2(e): softmax done in exp2 domain.
#define SM_SCALE 0.1803368801111204f

// ---------------------------------------------------------------------------
// fp32 -> bf16 cast, 8 elements/thread.
// ---------------------------------------------------------------------------
__global__ __launch_bounds__(256) void cast_bf16(
    const float* __restrict__ src, u16* __restrict__ dst, int n8)
{
    int i = blockIdx.x * 256 + threadIdx.x;
    if (i >= n8) return;
    float4 v0 = reinterpret_cast<const float4*>(src)[i * 2];
    float4 v1 = reinterpret_cast<const float4*>(src)[i * 2 + 1];
    uint4 o;
    o.x = pack_bf16(v0.x, v0.y);
    o.y = pack_bf16(v0.z, v0.w);
    o.z = pack_bf16(v1.x, v1.y);
    o.w = pack_bf16(v1.z, v1.w);
    reinterpret_cast<uint4*>(dst)[i] = o;
}

// ---------------------------------------------------------------------------
// Fused Wq/Wk/Wv transpose+convert: z in [0,48) -> head (z&15) of proj (z>>4).
// src fp32 [1024][64] per head -> dst bf16 [64][1024].  grid=(16,1,48).
// ---------------------------------------------------------------------------
__global__ __launch_bounds__(256) void transpose_qkv(
    const float* __restrict__ Wq, const float* __restrict__ Wk,
    const float* __restrict__ Wv, u16* __restrict__ dst)
{
    __shared__ float T[64][65];
    const int t = threadIdx.x;
    const int z = blockIdx.z;
    const int r0 = blockIdx.x * 64;
    const float* s = (z < 16 ? Wq : (z < 32 ? Wk : Wv)) + (size_t)(z & 15) * 65536;
    u16* d = dst + (size_t)z * 65536;
#pragma unroll
    for (int i = 0; i < 4; ++i) {
        int idx = i * 256 + t;
        int row = idx >> 4, col = (idx & 15) * 4;
        float4 v = *reinterpret_cast<const float4*>(&s[(size_t)(r0 + row) * 64 + col]);
        T[row][col] = v.x; T[row][col + 1] = v.y;
        T[row][col + 2] = v.z; T[row][col + 3] = v.w;
    }
    __syncthreads();
#pragma unroll
    for (int i = 0; i < 4; ++i) {
        int idx = i * 256 + t;
        int oc = idx >> 4, ok = (idx & 15) * 4;
        ushort4 o;
        o.x = bfu(T[ok][oc]);     o.y = bfu(T[ok + 1][oc]);
        o.z = bfu(T[ok + 2][oc]); o.w = bfu(T[ok + 3][oc]);
        *reinterpret_cast<ushort4*>(&d[(size_t)oc * 1024 + r0 + ok]) = o;
    }
}

// ---------------------------------------------------------------------------
// Generic transpose+convert (for Wo): src fp32 [R][C] -> dst bf16 [C][R].
// ---------------------------------------------------------------------------
__global__ __launch_bounds__(256) void transpose_bf16(
    const float* __restrict__ src, u16* __restrict__ dst, int R, int C)
{
    __shared__ float T[64][65];
    const int t = threadIdx.x;
    const int r0 = blockIdx.x * 64, c0 = blockIdx.y * 64;
#pragma unroll
    for (int i = 0; i < 4; ++i) {
        int idx = i * 256 + t;
        int row = idx >> 4, col = (idx & 15) * 4;
        float4 v = *reinterpret_cast<const float4*>(&src[(size_t)(r0 + row) * C + c0 + col]);
        T[row][col] = v.x; T[row][col + 1] = v.y;
        T[row][col + 2] = v.z; T[row][col + 3] = v.w;
    }
    __syncthreads();
#pragma unroll
    for (int i = 0; i < 4; ++i) {
        int idx = i * 256 + t;
        int oc = idx >> 4, ok = (idx & 15) * 4;
        ushort4 o;
        o.x = bfu(T[ok][oc]);     o.y = bfu(T[ok + 1][oc]);
        o.z = bfu(T[ok + 2][oc]); o.w = bfu(T[ok + 3][oc]);
        *reinterpret_cast<ushort4*>(&dst[(size_t)(c0 + oc) * R + r0 + ok]) = o;
    }
}

// ---------------------------------------------------------------------------
// bf16 MFMA GEMM (m97 structure: global_load_lds 16B, swizzled, BM=128 BN=64
// BK=64, 4 waves 2x2, 16 mfma/K-step/wave).
// fused=1: grid (32,48); by -> proj (by>>4: 0=q,1=k,2=vt), head (by&15).
//          Bt + by*65536 spans contiguous wqt/wkt/wvt.
// fused=0: grid (32,16); by = n-tile, C = Cf fp32 [4096][1024].
// ---------------------------------------------------------------------------
__global__ __launch_bounds__(256) void gemm_mfma(
    const u16* __restrict__ A, const u16* __restrict__ Bt,
    float* __restrict__ Cf, u16* __restrict__ Cq, u16* __restrict__ Ck,
    u16* __restrict__ Cvt, int fused)
{
    __shared__ u16 As[128 * 64];
    __shared__ u16 Bs[64 * 64];

    const int tid  = threadIdx.x;
    const int lane = tid & 63;
    const int w    = tid >> 6;
    const int g    = lane >> 4;
    const int c15  = lane & 15;
    const int wr   = w >> 1, wc = w & 1;
    const int m0   = blockIdx.x * 128;
    const int by   = blockIdx.y;

    const u16* Bb = Bt + (size_t)by * (64 * 1024);
    const int srow8  = lane >> 3;
    const int schunk = lane & 7;

    f32x4 acc[4][2];
#pragma unroll
    for (int mf = 0; mf < 4; ++mf)
#pragma unroll
        for (int nf = 0; nf < 2; ++nf) acc[mf][nf] = f32x4{0.f, 0.f, 0.f, 0.f};

    for (int k0 = 0; k0 < GK; k0 += 64) {
#pragma unroll
        for (int c = 0; c < 4; ++c) {
            int row = c * 32 + w * 8 + srow8;
            int gc = schunk ^ (row & 7);
            gl_lds16(A + (size_t)(m0 + row) * GK + k0 + gc * 8,
                     As + c * 2048 + w * 512);
        }
#pragma unroll
        for (int c = 0; c < 2; ++c) {
            int row = c * 32 + w * 8 + srow8;
            int gc = schunk ^ (row & 7);
            gl_lds16(Bb + (size_t)row * GK + k0 + gc * 8,
                     Bs + c * 2048 + w * 512);
        }
        __syncthreads();

#pragma unroll
        for (int kc = 0; kc < 2; ++kc) {
            bf16x8 a[4], b[2];
#pragma unroll
            for (int mf = 0; mf < 4; ++mf) {
                int row = wr * 64 + mf * 16 + c15;
                int ch = (kc * 4 + g) ^ (row & 7);
                a[mf] = *reinterpret_cast<const bf16x8*>(As + row * 64 + ch * 8);
            }
#pragma unroll
            for (int nf = 0; nf < 2; ++nf) {
                int row = wc * 32 + nf * 16 + c15;
                int ch = (kc * 4 + g) ^ (row & 7);
                b[nf] = *reinterpret_cast<const bf16x8*>(Bs + row * 64 + ch * 8);
            }
#pragma unroll
            for (int mf = 0; mf < 4; ++mf)
#pragma unroll
                for (int nf = 0; nf < 2; ++nf)
                    acc[mf][nf] = __builtin_amdgcn_mfma_f32_16x16x32_bf16(
                        a[mf], b[nf], acc[mf][nf], 0, 0, 0);
        }
        __syncthreads();
    }

    // ---- epilogue ----
    if (!fused) {
#pragma unroll
        for (int mf = 0; mf < 4; ++mf) {
            int m = m0 + wr * 64 + mf * 16 + g * 4;
#pragma unroll
            for (int nf = 0; nf < 2; ++nf) {
                int n = by * 64 + wc * 32 + nf * 16 + c15;
#pragma unroll
                for (int r = 0; r < 4; ++r)
                    Cf[(size_t)(m + r) * 1024 + n] = acc[mf][nf][r];
            }
        }
        return;
    }
    const int proj = by >> 4;
    const int head = by & 15;
    const int b = m0 >> 11, l0 = m0 & 2047;
    if (proj < 2) {
        u16* C = proj ? Ck : Cq;
        const size_t bh = ((size_t)(b * GH + head)) * GL * 64;
#pragma unroll
        for (int mf = 0; mf < 4; ++mf) {
            int l = l0 + wr * 64 + mf * 16 + g * 4;
#pragma unroll
            for (int nf = 0; nf < 2; ++nf) {
                int n = wc * 32 + nf * 16 + c15;
#pragma unroll
                for (int r = 0; r < 4; ++r)
                    C[bh + (size_t)(l + r) * 64 + n] = bfu(acc[mf][nf][r]);
            }
        }
    } else {
        const size_t bh = ((size_t)(b * GH + head)) * 64 * GL;
#pragma unroll
        for (int mf = 0; mf < 4; ++mf) {
            int l = l0 + wr * 64 + mf * 16 + g * 4;
#pragma unroll
            for (int nf = 0; nf < 2; ++nf) {
                int n = wc * 32 + nf * 16 + c15;
                ushort4 o;
                o.x = bfu(acc[mf][nf][0]); o.y = bfu(acc[mf][nf][1]);
                o.z = bfu(acc[mf][nf][2]); o.w = bfu(acc[mf][nf][3]);
                *reinterpret_cast<ushort4*>(&Cvt[bh + (size_t)n * GL + l]) = o;
            }
        }
    }
}

// ---------------------------------------------------------------------------
// One KV-tile step of swapped-operand flash attention for one 64-row q-tile.
// Scores pre-scaled into exp2 domain (SM_SCALE). Fully inlined.
// ---------------------------------------------------------------------------
__device__ __forceinline__ void attn_step(
    const u16* __restrict__ Kt, const u16* __restrict__ Vt, uint2* Pw,
    const bf16x8* qf, int qrow, int j0, int col, int g,
    float& m_run, float& l_run, f32x4* o_acc)
{
    f32x4 st[4];
#pragma unroll
    for (int nt = 0; nt < 4; ++nt) {
        int row = nt * 16 + col;
        bf16x8 kf0 = *reinterpret_cast<const bf16x8*>(Kt + row * 64 + (( g      ^ (row & 7)) * 8));
        bf16x8 kf1 = *reinterpret_cast<const bf16x8*>(Kt + row * 64 + (((4 + g) ^ (row & 7)) * 8));
        f32x4 z = f32x4{0.f, 0.f, 0.f, 0.f};
        z      = __builtin_amdgcn_mfma_f32_16x16x32_bf16(kf0, qf[0], z, 0, 0, 0);
        st[nt] = __builtin_amdgcn_mfma_f32_16x16x32_bf16(kf1, qf[1], z, 0, 0, 0);
    }

    float mx = -__builtin_inff();
#pragma unroll
    for (int nt = 0; nt < 4; ++nt)
#pragma unroll
        for (int r = 0; r < 4; ++r) {
            int kcol = j0 + nt * 16 + g * 4 + r;
            float s = (kcol <= qrow) ? st[nt][r] * SM_SCALE : -__builtin_inff();
            st[nt][r] = s;
            mx = fmaxf(mx, s);
        }
    mx = fmaxf(mx, __shfl_xor(mx, 16));
    mx = fmaxf(mx, __shfl_xor(mx, 32));
    const float mnew = fmaxf(m_run, mx);
    const float scl  = fexp2(m_run - mnew);
    float rsum = 0.f;
    unsigned pk[4][2];
#pragma unroll
    for (int nt = 0; nt < 4; ++nt) {
        float p0 = fexp2(st[nt][0] - mnew);
        float p1 = fexp2(st[nt][1] - mnew);
        float p2 = fexp2(st[nt][2] - mnew);
        float p3 = fexp2(st[nt][3] - mnew);
        rsum += (p0 + p1) + (p2 + p3);
        pk[nt][0] = pack_bf16(p0, p1);
        pk[nt][1] = pack_bf16(p2, p3);
    }
    rsum += __shfl_xor(rsum, 16);
    rsum += __shfl_xor(rsum, 32);
    l_run = l_run * scl + rsum;
    m_run = mnew;
#pragma unroll
    for (int nt = 0; nt < 4; ++nt) {
        o_acc[nt][0] *= scl; o_acc[nt][1] *= scl;
        o_acc[nt][2] *= scl; o_acc[nt][3] *= scl;
    }

#pragma unroll
    for (int nt = 0; nt < 4; ++nt) {
        int unit = (((nt * 2 + (g >> 1)) ^ (col & 7)) << 1) | (g & 1);
        uint2 u; u.x = pk[nt][0]; u.y = pk[nt][1];
        Pw[col * 16 + unit] = u;
    }
    bf16x8 pf[2];
#pragma unroll
    for (int c = 0; c < 2; ++c) {
        int chunk = (c * 4 + g) ^ (col & 7);
        pf[c] = *reinterpret_cast<const bf16x8*>(&Pw[col * 16 + chunk * 2]);
    }
#pragma unroll
    for (int nt = 0; nt < 4; ++nt) {
        int row = nt * 16 + col;
        bf16x8 vf0 = *reinterpret_cast<const bf16x8*>(Vt + row * 64 + (( g      ^ (row & 7)) * 8));
        bf16x8 vf1 = *reinterpret_cast<const bf16x8*>(Vt + row * 64 + (((4 + g) ^ (row & 7)) * 8));
        o_acc[nt] = __builtin_amdgcn_mfma_f32_16x16x32_bf16(vf0, pf[0], o_acc[nt], 0, 0, 0);
        o_acc[nt] = __builtin_amdgcn_mfma_f32_16x16x32_bf16(vf1, pf[1], o_acc[nt], 0, 0, 0);
    }
}

// ---------------------------------------------------------------------------
// Pair-balanced causal flash attention, double-buffered K/V via global_load_lds.
// 1D grid of 512 blocks (4 waves each). Decode: slot=bid&7 (XCD), idx=bid>>3,
// bh = slot + 8*(idx>>4), x = idx&15. Block handles q-tiles xa=x and xb=31-x
// of (b,h) bh -> exactly 33 tile-computes per block; K/V staged once per j0.
// ---------------------------------------------------------------------------
__global__ __launch_bounds__(256) void attn_mfma(
    const u16* __restrict__ qg, const u16* __restrict__ kg,
    const u16* __restrict__ vtg, u16* __restrict__ og)
{
    __shared__ u16 Ks[2][64 * 64];
    __shared__ u16 Vs[2][64 * 64];
    __shared__ uint2 Ps[4][256];

    const int tid  = threadIdx.x;
    const int lane = tid & 63;
    const int w    = tid >> 6;
    const int col  = lane & 15;
    const int g    = lane >> 4;

    const int bid  = blockIdx.x;
    const int slot = bid & 7;
    const int idx  = bid >> 3;
    const int bh   = slot + 8 * (idx >> 4);
    const int x    = idx & 15;
    const int xa   = x, xb = 31 - x;

    const size_t qkb  = (size_t)bh * GL * 64;
    const size_t vtbo = (size_t)bh * 64 * GL;

    const int qrowA = xa * 64 + w * 16 + col;
    const int qrowB = xb * 64 + w * 16 + col;
    bf16x8 qfA[2], qfB[2];
    qfA[0] = *reinterpret_cast<const bf16x8*>(qg + qkb + (size_t)qrowA * 64 + g * 8);
    qfA[1] = *reinterpret_cast<const bf16x8*>(qg + qkb + (size_t)qrowA * 64 + 32 + g * 8);
    qfB[0] = *reinterpret_cast<const bf16x8*>(qg + qkb + (size_t)qrowB * 64 + g * 8);
    qfB[1] = *reinterpret_cast<const bf16x8*>(qg + qkb + (size_t)qrowB * 64 + 32 + g * 8);

    // staging constants: call c, wave w covers units [(c*4+w)*64, +64)
    const int lrow = lane >> 3;
    const int sc   = (lane & 7) ^ lrow;   // pre-swizzled source chunk

    auto stage = [&](int t, int b) {
#pragma unroll
        for (int c = 0; c < 2; ++c) {
            const int ub  = (c * 4 + w) * 64;            // unit base
            const int row = (c * 4 + w) * 8 + lrow;      // tile row for this lane
            gl_lds16(kg + qkb + (size_t)(t * 64 + row) * 64 + sc * 8,
                     &Ks[b][ub * 8]);
            gl_lds16(vtg + vtbo + (size_t)row * GL + t * 64 + sc * 8,
                     &Vs[b][ub * 8]);
        }
    };

    float mA = -__builtin_inff(), lA = 0.f;
    float mB = -__builtin_inff(), lB = 0.f;
    f32x4 oA[4], oB[4];
#pragma unroll
    for (int nt = 0; nt < 4; ++nt) {
        oA[nt] = f32x4{0.f, 0.f, 0.f, 0.f};
        oB[nt] = f32x4{0.f, 0.f, 0.f, 0.f};
    }

    stage(0, 0);
    __syncthreads();

    const int last = xb;   // tile B spans j0t = 0..xb (tile A is a prefix)
    for (int t = 0; t <= last; ++t) {
        const int cur = t & 1;
        if (t < last) stage(t + 1, cur ^ 1);
        attn_step(Ks[cur], Vs[cur], Ps[w], qfB, qrowB, t * 64, col, g, mB, lB, oB);
        if (t <= xa)
            attn_step(Ks[cur], Vs[cur], Ps[w], qfA, qrowA, t * 64, col, g, mA, lA, oA);
        __syncthreads();   // drains stage(t+1) + all reads of buf cur done
    }

    // ---- epilogue ----
    const int b = bh >> 4, h = bh & 15;
    const float invA = 1.f / lA, invB = 1.f / lB;
#pragma unroll
    for (int nt = 0; nt < 4; ++nt) {
        ushort4 ov;
        ov.x = bfu(oA[nt][0] * invA); ov.y = bfu(oA[nt][1] * invA);
        ov.z = bfu(oA[nt][2] * invA); ov.w = bfu(oA[nt][3] * invA);
        *reinterpret_cast<ushort4*>(
            og + ((size_t)(b * GL + qrowA)) * 1024 + h * 64 + nt * 16 + g * 4) = ov;
        ushort4 ow;
        ow.x = bfu(oB[nt][0] * invB); ow.y = bfu(oB[nt][1] * invB);
        ow.z = bfu(oB[nt][2] * invB); ow.w = bfu(oB[nt][3] * invB);
        *reinterpret_cast<ushort4*>(
            og + ((size_t)(b * GL + qrowB)) * 1024 + h * 64 + nt * 16 + g * 4) = ow;
    }
}

// ---------------------------------------------------------------------------
extern "C" void kernel_launch(void* const* d_in, const int* in_sizes, int n_in,
                              void* d_out, int out_size, void* d_ws, size_t ws_size,
                              hipStream_t stream) {
    const float* emb = (const float*)d_in[0];
    const float* Wq  = (const float*)d_in[1];
    const float* Wk  = (const float*)d_in[2];
    const float* Wv  = (const float*)d_in[3];
    const float* Wo  = (const float*)d_in[4];
    float* out = (float*)d_out;

    char* ws = (char*)d_ws;
    u16* qb   = (u16*)(ws);
    u16* kb   = (u16*)(ws + ( 8u << 20));
    u16* vtb  = (u16*)(ws + (16u << 20));
    u16* ab   = (u16*)(ws + (24u << 20));
    u16* embb = (u16*)(ws + (32u << 20));
    u16* wqt  = (u16*)(ws + (40u << 20));   // 48 x 64 x 1024 contiguous (q,k,v)
    u16* wot  = (u16*)(ws + (46u << 20));

    dim3 blk(256);

    cast_bf16<<<dim3(2048), blk, 0, stream>>>(emb, embb, GM * GK / 8);
    transpose_qkv<<<dim3(16, 1, 48), blk, 0, stream>>>(Wq, Wk, Wv, wqt);
    transpose_bf16<<<dim3(16, 16, 1), blk, 0, stream>>>(Wo, wot, 1024, 1024);

    // fused Q/K/V projections (one dispatch, 48 n-slices)
    gemm_mfma<<<dim3(GM / 128, 48), blk, 0, stream>>>(
        embb, wqt, nullptr, qb, kb, vtb, 1);

    // pair-balanced attention
    attn_mfma<<<dim3(512), blk, 0, stream>>>(qb, kb, vtb, ab);

    // output projection
    gemm_mfma<<<dim3(GM / 128, 16), blk, 0, stream>>>(
        ab, wot, out, nullptr, nullptr, nullptr, 0);
}